// Round 21
// baseline (643.226 us; speedup 1.0000x reference)
//
#include <hip/hip_runtime.h>

#define THREADS 256

typedef float v2f __attribute__((ext_vector_type(2)));

// clamp-free fast tanh: 1 - 2/(e^2x + 1).
__device__ __forceinline__ float ftanh(float x) {
    float t = __expf(2.0f * x);
    return fmaf(-2.0f, __builtin_amdgcn_rcpf(t + 1.0f), 1.0f);
}

__device__ __forceinline__ int clampi(int v, int lo, int hi) {
    return v < lo ? lo : (v > hi ? hi : v);
}

// ---------------- CSR build: histogram -> 2-level coalesced scan -> scatter(packed rc) ----------------

__global__ __launch_bounds__(THREADS) void hist_kernel(
    const int* __restrict__ row, int* __restrict__ cnt, int E, int N)
{
    int e = blockIdx.x * THREADS + threadIdx.x;
    if (e < E) {
        int r = row[e];
        if ((unsigned)r < (unsigned)N) atomicAdd(&cnt[r], 1);
    }
}

// level 1: per-block coalesced exclusive scan; block totals to bsum
__global__ __launch_bounds__(THREADS) void scan_blocks(
    const int* __restrict__ cnt, int* __restrict__ start,
    int* __restrict__ bsum, int N)
{
    __shared__ int ssum[THREADS];
    int t = threadIdx.x;
    int i = blockIdx.x * THREADS + t;
    int v = (i < N) ? cnt[i] : 0;
    ssum[t] = v;
    __syncthreads();
    for (int d = 1; d < THREADS; d <<= 1) {
        int u = (t >= d) ? ssum[t - d] : 0;
        __syncthreads();
        ssum[t] += u;
        __syncthreads();
    }
    if (i < N) start[i] = ssum[t] - v;      // block-local exclusive
    if (t == THREADS - 1) bsum[blockIdx.x] = ssum[t];
}

// level 2: exclusive scan of block sums (nb <= 256 guaranteed by N <= 65535)
__global__ __launch_bounds__(THREADS) void scan_bsums(
    int* __restrict__ bsum, int nb)
{
    __shared__ int ssum[THREADS];
    int t = threadIdx.x;
    int v = (t < nb) ? bsum[t] : 0;
    ssum[t] = v;
    __syncthreads();
    for (int d = 1; d < THREADS; d <<= 1) {
        int u = (t >= d) ? ssum[t - d] : 0;
        __syncthreads();
        ssum[t] += u;
        __syncthreads();
    }
    if (t < nb) bsum[t] = ssum[t] - v;      // exclusive block offsets
}

// scatter with block offset folded in (replaces scan_add pass):
// pos = block-local atomic bump + bsum[node_block]. rc packed (N <= 65535).
__global__ __launch_bounds__(THREADS) void scatter_rc_kernel(
    const int* __restrict__ row, const int* __restrict__ col,
    int* __restrict__ start, const int* __restrict__ bsum,
    int* __restrict__ rc, int E, int N)
{
    int e = blockIdx.x * THREADS + threadIdx.x;
    if (e < E) {
        int r = row[e];
        if ((unsigned)r < (unsigned)N) {
            int pos = atomicAdd(&start[r], 1) + bsum[r >> 8];
            if ((unsigned)pos < (unsigned)E) {
                int c = clampi(col[e], 0, N - 1);
                rc[pos] = (int)(((unsigned)r << 16) | (unsigned)c);
            }
        }
    }
}

// ---------------- edge MLP (v_pk_fma_f32: 2 f32 MACs/instr) + wave-segmented reduce ----------------
// Weights read directly from global with wave-uniform indices -> s_load (scalar
// pipe). Matmuls on float2 vectors lower to v_pk_fma_f32 (full-rate packed FP32
// FMA), halving matmul VALU issue vs scalar v_fmac with bit-identical results.

__global__ __launch_bounds__(THREADS, 4) void edge_kernel_sorted(
    const int* __restrict__ rc,
    const float* __restrict__ coord, const float* __restrict__ h,
    const float* __restrict__ Wm1, const float* __restrict__ bm1,
    const float* __restrict__ Wm2, const float* __restrict__ bm2,
    const float* __restrict__ Wc1, const float* __restrict__ bc1,
    const float* __restrict__ Wc2,
    float* __restrict__ num, float* __restrict__ agg, int E, int N)
{
    int e = blockIdx.x * THREADS + threadIdx.x;
    int lane = threadIdx.x & 63;

    int r = 0, c = 0, seg = -1;
    if (e < E) {
        unsigned p = (unsigned)__builtin_nontemporal_load(&rc[e]);
        r = clampi((int)(p >> 16), 0, N - 1);
        c = clampi((int)(p & 0xFFFFu), 0, N - 1);
        seg = r;
    }

    float rx = coord[(size_t)r * 3 + 0] - coord[(size_t)c * 3 + 0];
    float ry = coord[(size_t)r * 3 + 1] - coord[(size_t)c * 3 + 1];
    float rz = coord[(size_t)r * 3 + 2] - coord[(size_t)c * 3 + 2];
    float d2 = rx * rx + ry * ry + rz * rz;

    float x[33];
    {
        const float4* hr = (const float4*)(h + (size_t)r * 16);
        const float4* hc = (const float4*)(h + (size_t)c * 16);
#pragma unroll
        for (int q = 0; q < 4; ++q) {
            float4 a = hr[q];
            x[4 * q + 0] = a.x; x[4 * q + 1] = a.y;
            x[4 * q + 2] = a.z; x[4 * q + 3] = a.w;
        }
#pragma unroll
        for (int q = 0; q < 4; ++q) {
            float4 b = hc[q];
            x[16 + 4 * q + 0] = b.x; x[16 + 4 * q + 1] = b.y;
            x[16 + 4 * q + 2] = b.z; x[16 + 4 * q + 3] = b.w;
        }
        x[32] = d2;
    }

    // layer 1: 33 -> 32, packed-f32 pairs along output dim
    v2f acc2[16];
#pragma unroll
    for (int j = 0; j < 16; ++j) acc2[j] = v2f{bm1[2 * j], bm1[2 * j + 1]};
#pragma unroll
    for (int k = 0; k < 33; ++k) {
        float xk = x[k];
        v2f xx = {xk, xk};
        const v2f* w2 = (const v2f*)(Wm1 + k * 32);
#pragma unroll
        for (int j = 0; j < 16; ++j)
            acc2[j] = __builtin_elementwise_fma(xx, w2[j], acc2[j]);
    }
    float t1[32];
#pragma unroll
    for (int j = 0; j < 16; ++j) {
        t1[2 * j + 0] = ftanh(acc2[j].x);
        t1[2 * j + 1] = ftanh(acc2[j].y);
    }

    // layer 2: 32 -> 32
#pragma unroll
    for (int j = 0; j < 16; ++j) acc2[j] = v2f{bm2[2 * j], bm2[2 * j + 1]};
#pragma unroll
    for (int k = 0; k < 32; ++k) {
        float xk = t1[k];
        v2f xx = {xk, xk};
        const v2f* w2 = (const v2f*)(Wm2 + k * 32);
#pragma unroll
        for (int j = 0; j < 16; ++j)
            acc2[j] = __builtin_elementwise_fma(xx, w2[j], acc2[j]);
    }

    // v[0..31] = m, v[32..34] = trans
    float v[35];
#pragma unroll
    for (int j = 0; j < 16; ++j) {
        v[2 * j + 0] = ftanh(acc2[j].x);
        v[2 * j + 1] = ftanh(acc2[j].y);
    }

    // coord gate: 32 -> 32 -> 1
#pragma unroll
    for (int j = 0; j < 16; ++j) acc2[j] = v2f{bc1[2 * j], bc1[2 * j + 1]};
#pragma unroll
    for (int k = 0; k < 32; ++k) {
        float xk = v[k];
        v2f xx = {xk, xk};
        const v2f* w2 = (const v2f*)(Wc1 + k * 32);
#pragma unroll
        for (int j = 0; j < 16; ++j)
            acc2[j] = __builtin_elementwise_fma(xx, w2[j], acc2[j]);
    }
    float cw = 0.0f;
#pragma unroll
    for (int j = 0; j < 16; ++j) {
        cw = fmaf(ftanh(acc2[j].x), Wc2[2 * j + 0], cw);
        cw = fmaf(ftanh(acc2[j].y), Wc2[2 * j + 1], cw);
    }
    cw = ftanh(cw);

    float s = cw * __builtin_amdgcn_rcpf(__builtin_amdgcn_sqrtf(d2) + 1.0f);
    v[32] = rx * s; v[33] = ry * s; v[34] = rz * s;

    // wave-level segmented inclusive scan; rows contiguous after sort.
#define SEGSTEP(D)                                                \
    {                                                             \
        int rup = __shfl_up(seg, D);                              \
        bool ok = (lane >= D) && (rup == seg);                    \
        _Pragma("unroll")                                         \
        for (int k = 0; k < 35; ++k) {                            \
            float o = __shfl_up(v[k], D);                         \
            v[k] += ok ? o : 0.0f;                                \
        }                                                         \
    }
    SEGSTEP(1) SEGSTEP(2) SEGSTEP(4) SEGSTEP(8) SEGSTEP(16) SEGSTEP(32)
#undef SEGSTEP

    int rdn = __shfl_down(seg, 1);
    bool tail = (lane == 63) || (rdn != seg);
    if (tail && seg >= 0) {
        float* ar = agg + (size_t)seg * 32;
#pragma unroll
        for (int k = 0; k < 32; ++k) atomicAdd(ar + k, v[k]);
        float* nr = num + (size_t)seg * 3;
        atomicAdd(nr + 0, v[32]);
        atomicAdd(nr + 1, v[33]);
        atomicAdd(nr + 2, v[34]);
    }
}

// ---------------- fallback: per-edge atomics, f32 LDS weights (round-1, proven) ----------------

__global__ __launch_bounds__(THREADS, 4) void edge_kernel_naive(
    const int* __restrict__ row, const int* __restrict__ col,
    const float* __restrict__ coord, const float* __restrict__ h,
    const float* __restrict__ Wm1, const float* __restrict__ bm1,
    const float* __restrict__ Wm2, const float* __restrict__ bm2,
    const float* __restrict__ Wc1, const float* __restrict__ bc1,
    const float* __restrict__ Wc2,
    float* __restrict__ num, float* __restrict__ agg, int E, int N)
{
    __shared__ float sWm1[33 * 32];
    __shared__ float sWm2[32 * 32];
    __shared__ float sWc1[32 * 32];
    __shared__ float sbm1[32], sbm2[32], sbc1[32], sWc2[32];

    for (int i = threadIdx.x; i < 33 * 32; i += THREADS) sWm1[i] = Wm1[i];
    for (int i = threadIdx.x; i < 32 * 32; i += THREADS) sWm2[i] = Wm2[i];
    for (int i = threadIdx.x; i < 32 * 32; i += THREADS) sWc1[i] = Wc1[i];
    if (threadIdx.x < 32) {
        sbm1[threadIdx.x] = bm1[threadIdx.x];
        sbm2[threadIdx.x] = bm2[threadIdx.x];
        sbc1[threadIdx.x] = bc1[threadIdx.x];
        sWc2[threadIdx.x] = Wc2[threadIdx.x];
    }
    __syncthreads();

    int e = blockIdx.x * THREADS + threadIdx.x;
    if (e >= E) return;

    int r = clampi(row[e], 0, N - 1);
    int c = clampi(col[e], 0, N - 1);

    float rx = coord[(size_t)r * 3 + 0] - coord[(size_t)c * 3 + 0];
    float ry = coord[(size_t)r * 3 + 1] - coord[(size_t)c * 3 + 1];
    float rz = coord[(size_t)r * 3 + 2] - coord[(size_t)c * 3 + 2];
    float d2 = rx * rx + ry * ry + rz * rz;

    float x[33];
    {
        const float4* hr = (const float4*)(h + (size_t)r * 16);
        const float4* hc = (const float4*)(h + (size_t)c * 16);
#pragma unroll
        for (int q = 0; q < 4; ++q) {
            float4 a = hr[q];
            x[4 * q + 0] = a.x; x[4 * q + 1] = a.y;
            x[4 * q + 2] = a.z; x[4 * q + 3] = a.w;
        }
#pragma unroll
        for (int q = 0; q < 4; ++q) {
            float4 b = hc[q];
            x[16 + 4 * q + 0] = b.x; x[16 + 4 * q + 1] = b.y;
            x[16 + 4 * q + 2] = b.z; x[16 + 4 * q + 3] = b.w;
        }
        x[32] = d2;
    }

    float acc[32];
#pragma unroll
    for (int j = 0; j < 32; ++j) acc[j] = sbm1[j];
#pragma unroll
    for (int k = 0; k < 33; ++k) {
        float xk = x[k];
        const float4* w4 = (const float4*)(sWm1 + k * 32);
#pragma unroll
        for (int q = 0; q < 8; ++q) {
            float4 w = w4[q];
            acc[4 * q + 0] = fmaf(xk, w.x, acc[4 * q + 0]);
            acc[4 * q + 1] = fmaf(xk, w.y, acc[4 * q + 1]);
            acc[4 * q + 2] = fmaf(xk, w.z, acc[4 * q + 2]);
            acc[4 * q + 3] = fmaf(xk, w.w, acc[4 * q + 3]);
        }
    }
    float t1[32];
#pragma unroll
    for (int j = 0; j < 32; ++j) t1[j] = ftanh(acc[j]);

#pragma unroll
    for (int j = 0; j < 32; ++j) acc[j] = sbm2[j];
#pragma unroll
    for (int k = 0; k < 32; ++k) {
        float xk = t1[k];
        const float4* w4 = (const float4*)(sWm2 + k * 32);
#pragma unroll
        for (int q = 0; q < 8; ++q) {
            float4 w = w4[q];
            acc[4 * q + 0] = fmaf(xk, w.x, acc[4 * q + 0]);
            acc[4 * q + 1] = fmaf(xk, w.y, acc[4 * q + 1]);
            acc[4 * q + 2] = fmaf(xk, w.z, acc[4 * q + 2]);
            acc[4 * q + 3] = fmaf(xk, w.w, acc[4 * q + 3]);
        }
    }
    float m[32];
#pragma unroll
    for (int j = 0; j < 32; ++j) m[j] = ftanh(acc[j]);

#pragma unroll
    for (int j = 0; j < 32; ++j) acc[j] = sbc1[j];
#pragma unroll
    for (int k = 0; k < 32; ++k) {
        float xk = m[k];
        const float4* w4 = (const float4*)(sWc1 + k * 32);
#pragma unroll
        for (int q = 0; q < 8; ++q) {
            float4 w = w4[q];
            acc[4 * q + 0] = fmaf(xk, w.x, acc[4 * q + 0]);
            acc[4 * q + 1] = fmaf(xk, w.y, acc[4 * q + 1]);
            acc[4 * q + 2] = fmaf(xk, w.z, acc[4 * q + 2]);
            acc[4 * q + 3] = fmaf(xk, w.w, acc[4 * q + 3]);
        }
    }
    float cw = 0.0f;
#pragma unroll
    for (int j = 0; j < 32; ++j) cw = fmaf(ftanh(acc[j]), sWc2[j], cw);
    cw = ftanh(cw);

    float s = cw * __builtin_amdgcn_rcpf(__builtin_amdgcn_sqrtf(d2) + 1.0f);

    float* nr = num + (size_t)r * 3;
    atomicAdd(nr + 0, rx * s);
    atomicAdd(nr + 1, ry * s);
    atomicAdd(nr + 2, rz * s);
    float* ar = agg + (size_t)r * 32;
#pragma unroll
    for (int k = 0; k < 32; ++k) atomicAdd(ar + k, m[k]);
}

// ---------------- node update (now zeroes num/agg after reading -> no 2nd memset) ----------------

__global__ __launch_bounds__(THREADS, 4) void node_kernel(
    const float* __restrict__ coord_in, const float* __restrict__ h_in,
    float* __restrict__ num, float* __restrict__ agg,
    const int* __restrict__ cnt, const float* __restrict__ mask,
    const float* __restrict__ Wn1, const float* __restrict__ bn1,
    const float* __restrict__ Wn2, const float* __restrict__ bn2,
    float* __restrict__ coord_out, float* __restrict__ h_out, int N)
{
    __shared__ float sWn1[48 * 32];
    __shared__ float sWn2[32 * 16];
    __shared__ float sbn1[32], sbn2[16];

    for (int i = threadIdx.x; i < 48 * 32; i += THREADS) sWn1[i] = Wn1[i];
    for (int i = threadIdx.x; i < 32 * 16; i += THREADS) sWn2[i] = Wn2[i];
    if (threadIdx.x < 32) sbn1[threadIdx.x] = bn1[threadIdx.x];
    if (threadIdx.x < 16) sbn2[threadIdx.x] = bn2[threadIdx.x];
    __syncthreads();

    int i = blockIdx.x * THREADS + threadIdx.x;
    if (i >= N) return;

    float msk = mask[i];
    float inv_cnt = __builtin_amdgcn_rcpf(fmaxf((float)cnt[i], 1.0f));

#pragma unroll
    for (int dd = 0; dd < 3; ++dd) {
        float cv = coord_in[(size_t)i * 3 + dd];
        float ov = cv + num[(size_t)i * 3 + dd] * inv_cnt;
        coord_out[(size_t)i * 3 + dd] = ov * msk + cv * (1.0f - msk);
        num[(size_t)i * 3 + dd] = 0.0f;   // ready for next step
    }

    float hv[16];
    float x[48];
    {
        const float4* hp = (const float4*)(h_in + (size_t)i * 16);
#pragma unroll
        for (int q = 0; q < 4; ++q) {
            float4 a = hp[q];
            hv[4 * q + 0] = a.x; hv[4 * q + 1] = a.y;
            hv[4 * q + 2] = a.z; hv[4 * q + 3] = a.w;
            x[4 * q + 0] = a.x; x[4 * q + 1] = a.y;
            x[4 * q + 2] = a.z; x[4 * q + 3] = a.w;
        }
        float4* ap = (float4*)(agg + (size_t)i * 32);
#pragma unroll
        for (int q = 0; q < 8; ++q) {
            float4 a = ap[q];
            x[16 + 4 * q + 0] = a.x; x[16 + 4 * q + 1] = a.y;
            x[16 + 4 * q + 2] = a.z; x[16 + 4 * q + 3] = a.w;
            ap[q] = float4{0.0f, 0.0f, 0.0f, 0.0f};   // ready for next step
        }
    }

    float acc[32];
#pragma unroll
    for (int j = 0; j < 32; ++j) acc[j] = sbn1[j];
#pragma unroll
    for (int k = 0; k < 48; ++k) {
        float xk = x[k];
        const float4* w4 = (const float4*)(sWn1 + k * 32);
#pragma unroll
        for (int q = 0; q < 8; ++q) {
            float4 w = w4[q];
            acc[4 * q + 0] = fmaf(xk, w.x, acc[4 * q + 0]);
            acc[4 * q + 1] = fmaf(xk, w.y, acc[4 * q + 1]);
            acc[4 * q + 2] = fmaf(xk, w.z, acc[4 * q + 2]);
            acc[4 * q + 3] = fmaf(xk, w.w, acc[4 * q + 3]);
        }
    }
    float t[32];
#pragma unroll
    for (int j = 0; j < 32; ++j) t[j] = ftanh(acc[j]);

    float acc2[16];
#pragma unroll
    for (int j = 0; j < 16; ++j) acc2[j] = sbn2[j];
#pragma unroll
    for (int k = 0; k < 32; ++k) {
        float xk = t[k];
        const float4* w4 = (const float4*)(sWn2 + k * 16);
#pragma unroll
        for (int q = 0; q < 4; ++q) {
            float4 w = w4[q];
            acc2[4 * q + 0] = fmaf(xk, w.x, acc2[4 * q + 0]);
            acc2[4 * q + 1] = fmaf(xk, w.y, acc2[4 * q + 1]);
            acc2[4 * q + 2] = fmaf(xk, w.z, acc2[4 * q + 2]);
            acc2[4 * q + 3] = fmaf(xk, w.w, acc2[4 * q + 3]);
        }
    }

    float hn[16];
    float mean = 0.0f;
#pragma unroll
    for (int j = 0; j < 16; ++j) { hn[j] = hv[j] + acc2[j]; mean += hn[j]; }
    mean *= (1.0f / 16.0f);
    float var = 0.0f;
#pragma unroll
    for (int j = 0; j < 16; ++j) { float d = hn[j] - mean; var = fmaf(d, d, var); }
    var *= (1.0f / 16.0f);
    float stdv = __builtin_amdgcn_sqrtf(var + 1e-5f);
    float sc = __builtin_amdgcn_rsqf(stdv);   // (var+eps)^(-1/4)

#pragma unroll
    for (int j = 0; j < 16; ++j) {
        h_out[(size_t)i * 16 + j] = hn[j] * sc * msk + hv[j] * (1.0f - msk);
    }
}

extern "C" void kernel_launch(void* const* d_in, const int* in_sizes, int n_in,
                              void* d_out, int out_size, void* d_ws, size_t ws_size,
                              hipStream_t stream) {
    const int*   edge_index = (const int*)d_in[0];
    const float* coord      = (const float*)d_in[1];
    const float* h          = (const float*)d_in[2];
    const float* fire       = (const float*)d_in[3];
    const float* Wm1 = (const float*)d_in[4];
    const float* bm1 = (const float*)d_in[5];
    const float* Wm2 = (const float*)d_in[6];
    const float* bm2 = (const float*)d_in[7];
    const float* Wc1 = (const float*)d_in[8];
    const float* bc1 = (const float*)d_in[9];
    const float* Wc2 = (const float*)d_in[10];
    const float* Wn1 = (const float*)d_in[11];
    const float* bn1 = (const float*)d_in[12];
    const float* Wn2 = (const float*)d_in[13];
    const float* bn2 = (const float*)d_in[14];

    const int E = in_sizes[0] / 2;
    const int N = in_sizes[1] / 3;
    const int* row = edge_index;
    const int* col = edge_index + E;

    // ws layout: num 3N f32 | agg 32N f32 | cnth N i32 | startA N i32 |
    //            bsum 256 i32 | rc E i32
    float* ws     = (float*)d_ws;
    float* num    = ws;
    float* agg    = ws + (size_t)N * 3;
    int*   cnth   = (int*)(ws + (size_t)N * 35);
    int*   startA = cnth + N;
    int*   bsum   = startA + N;
    int*   rc     = bsum + 256;

    float* out_coord = (float*)d_out;
    float* out_h     = (float*)d_out + (size_t)N * 3;

    const int eb = (E + THREADS - 1) / THREADS;
    const int nb = (N + THREADS - 1) / THREADS;

    const size_t need_sorted =
        ((size_t)N * 37 + 256 + (size_t)E) * sizeof(float) + (1u << 20);

    if (ws_size >= need_sorted && N <= 65535) {
        // ---- one-time CSR build with packed (row<<16|col) stream ----
        (void)hipMemsetAsync(d_ws, 0, (size_t)N * 36 * sizeof(float), stream);
        hist_kernel<<<eb, THREADS, 0, stream>>>(row, cnth, E, N);
        scan_blocks<<<nb, THREADS, 0, stream>>>(cnth, startA, bsum, N);
        scan_bsums<<<1, THREADS, 0, stream>>>(bsum, nb);
        scatter_rc_kernel<<<eb, THREADS, 0, stream>>>(row, col, startA, bsum, rc, E, N);

        edge_kernel_sorted<<<eb, THREADS, 0, stream>>>(rc, coord, h,
            Wm1, bm1, Wm2, bm2, Wc1, bc1, Wc2, num, agg, E, N);
        node_kernel<<<nb, THREADS, 0, stream>>>(coord, h, num, agg, cnth, fire,
            Wn1, bn1, Wn2, bn2, out_coord, out_h, N);

        // num/agg were zeroed by node_kernel; no memset needed here
        edge_kernel_sorted<<<eb, THREADS, 0, stream>>>(rc, out_coord, out_h,
            Wm1, bm1, Wm2, bm2, Wc1, bc1, Wc2, num, agg, E, N);
        node_kernel<<<nb, THREADS, 0, stream>>>(out_coord, out_h, num, agg, cnth, fire + N,
            Wn1, bn1, Wn2, bn2, out_coord, out_h, N);
    } else {
        // ---- fallback: proven round-1 atomic path (7.2 MB) ----
        (void)hipMemsetAsync(d_ws, 0, (size_t)N * 36 * sizeof(float), stream);
        hist_kernel<<<eb, THREADS, 0, stream>>>(row, cnth, E, N);

        edge_kernel_naive<<<eb, THREADS, 0, stream>>>(row, col, coord, h,
            Wm1, bm1, Wm2, bm2, Wc1, bc1, Wc2, num, agg, E, N);
        node_kernel<<<nb, THREADS, 0, stream>>>(coord, h, num, agg, cnth, fire,
            Wn1, bn1, Wn2, bn2, out_coord, out_h, N);

        edge_kernel_naive<<<eb, THREADS, 0, stream>>>(row, col, out_coord, out_h,
            Wm1, bm1, Wm2, bm2, Wc1, bc1, Wc2, num, agg, E, N);
        node_kernel<<<nb, THREADS, 0, stream>>>(out_coord, out_h, num, agg, cnth, fire + N,
            Wn1, bn1, Wn2, bn2, out_coord, out_h, N);
    }
}